// Round 7
// baseline (122.521 us; speedup 1.0000x reference)
//
#include <hip/hip_runtime.h>

#define NB  4096
#define SS  102
#define SSP 104
#define HID 8
#define RS  0.72134752044448170368f   // 0.5 (score scale) * log2(e), folded into q

typedef float v2f __attribute__((ext_vector_type(2)));

// dot(row8, W-row i) with W a kernel-arg pointer and i compile-time constant
// -> all W[] reads are wave-uniform: compiler emits s_load (weights live in SGPRs).
#define DOT8(A, B, W, i) \
    ((A).x*(W)[(i)*8+0] + (A).y*(W)[(i)*8+1] + (A).z*(W)[(i)*8+2] + (A).w*(W)[(i)*8+3] + \
     (B).x*(W)[(i)*8+4] + (B).y*(W)[(i)*8+5] + (B).z*(W)[(i)*8+6] + (B).w*(W)[(i)*8+7])

// LDS (9856 B total -> 16 blocks/CU co-resident, thread-cap-limited):
//  sQ : [2][104][4] rotated+pre-scaled q (rows 102,103 zero).  After the q-fragment
//       loads in phase 2 this region is dead and is REUSED as comb [104][8]
//       (row-major, head h at cols 4h..4h+3) — guarded by a barrier.
//  sK : [2][102][4] rotated k
//  sV : [2][102][4] projected v
__global__ __launch_bounds__(128) void mha_fused_kernel(
    const float* __restrict__ query, const float* __restrict__ key,
    const float* __restrict__ value, const float* __restrict__ wq,
    const float* __restrict__ wk, const float* __restrict__ wv,
    const float* __restrict__ wo, float* __restrict__ out)
{
    __shared__ float sQ[2 * SSP * 4];    // 832 floats (also comb)
    __shared__ float sK[2 * SS * 4];     // 816
    __shared__ float sV[2 * SS * 4];     // 816

    const int t = threadIdx.x;
    const int b = blockIdx.x;

    // ---- phase 0+1: row-per-thread load + project + rotary, all in registers ----
    // Thread t owns row t: 6 coalesced dwordx4 loads (32 B/lane), zero LDS staging.
    if (t < SS) {
        const size_t boff = (size_t)b * (SS * HID);
        const float4* q4 = (const float4*)(query + boff) + 2 * t;
        const float4* k4 = (const float4*)(key   + boff) + 2 * t;
        const float4* v4 = (const float4*)(value + boff) + 2 * t;
        const float4 qa = q4[0], qb = q4[1];
        const float4 ka = k4[0], kb = k4[1];
        const float4 va = v4[0], vb = v4[1];
        // per-row trig: 2 calls, hidden under the ~700-cyc global-load latency
        const float sn = sinf((float)t), cn = cosf((float)t);

        // reference broadcast quirk: head0 scaled by sin(row), head1 by cos(row);
        // rotary pair: e' = (e - o)*wr, o' = (o + e)*wr.  q folds RS so the
        // softmax can use raw v_exp_f32 (base-2).
#pragma unroll
        for (int h = 0; h < 2; ++h) {
            const float wrk = h ? cn : sn;
            const float wrq = wrk * RS;
            float y[4], z[4];
#pragma unroll
            for (int u = 0; u < 2; ++u) {
                const int i0 = h * 4 + 2 * u;
                const float x0 = DOT8(qa, qb, wq, i0), x1 = DOT8(qa, qb, wq, i0 + 1);
                y[2*u] = (x0 - x1) * wrq;  y[2*u+1] = (x1 + x0) * wrq;
                const float k0 = DOT8(ka, kb, wk, i0), k1 = DOT8(ka, kb, wk, i0 + 1);
                z[2*u] = (k0 - k1) * wrk;  z[2*u+1] = (k1 + k0) * wrk;
            }
            ((float4*)sQ)[h * SSP + t] = make_float4(y[0], y[1], y[2], y[3]);
            ((float4*)sK)[h * SS  + t] = make_float4(z[0], z[1], z[2], z[3]);
            const float f0 = DOT8(va, vb, wv, h*4+0), f1 = DOT8(va, vb, wv, h*4+1);
            const float f2 = DOT8(va, vb, wv, h*4+2), f3 = DOT8(va, vb, wv, h*4+3);
            ((float4*)sV)[h * SS + t] = make_float4(f0, f1, f2, f3);
        }
    } else if (t < SSP) {
        // zero-pad q rows 102,103 (both heads); K/V rows >101 are never read
        ((float4*)sQ)[t]       = make_float4(0.f, 0.f, 0.f, 0.f);
        ((float4*)sQ)[SSP + t] = make_float4(0.f, 0.f, 0.f, 0.f);
    }
    __syncthreads();

    // ---- phase 2: attention. wave = head h, full 102-key range (no combine). ----
    // Each lane owns 2 q-rows packed as v2f (v_pk_fma_f32); K/V rows arrive as
    // wave-uniform ds_read_b128 broadcasts with register-rotating prefetch
    // (the baseline inner loop, verbatim, 102 iterations).
    const int wid = t >> 6, lane = t & 63;
    const int h = wid;
    const bool act = lane < 52;
    v2f q0, q1, q2, q3;
    if (act) {
        const float4* Q4 = (const float4*)sQ + h * SSP + 2 * lane;
        const float4 qa = Q4[0], qc = Q4[1];
        q0 = (v2f){qa.x, qc.x}; q1 = (v2f){qa.y, qc.y};
        q2 = (v2f){qa.z, qc.z}; q3 = (v2f){qa.w, qc.w};
    }
    __syncthreads();   // all q reads done -> comb may overlay sQ

    if (act) {
        v2f acc0 = {0.f,0.f}, acc1 = {0.f,0.f}, acc2 = {0.f,0.f}, acc3 = {0.f,0.f};
        v2f l = {0.f, 0.f};
        const float4* K4 = (const float4*)sK + h * SS;
        const float4* V4 = (const float4*)sV + h * SS;
        float4 kk = K4[0], vvv = V4[0];
#pragma unroll 2
        for (int k = 1; k < SS; ++k) {
            const float4 nk = K4[k], nv = V4[k];
            v2f s = q0 * kk.x + q1 * kk.y + q2 * kk.z + q3 * kk.w;
            v2f p;
            p.x = __builtin_amdgcn_exp2f(s.x);
            p.y = __builtin_amdgcn_exp2f(s.y);
            l += p;
            acc0 += p * vvv.x; acc1 += p * vvv.y;
            acc2 += p * vvv.z; acc3 += p * vvv.w;
            kk = nk; vvv = nv;
        }
        {
            v2f s = q0 * kk.x + q1 * kk.y + q2 * kk.z + q3 * kk.w;
            v2f p;
            p.x = __builtin_amdgcn_exp2f(s.x);
            p.y = __builtin_amdgcn_exp2f(s.y);
            l += p;
            acc0 += p * vvv.x; acc1 += p * vvv.y;
            acc2 += p * vvv.z; acc3 += p * vvv.w;
        }
        // normalize inline and write head-combined rows: comb[row][8], head h
        // at float4 slot row*2+h (overlays dead sQ; rows 102,103 land in pad
        // slots and are never read by phase 3).
        const float ix = 1.f / l.x, iy = 1.f / l.y;
        float4* comb = (float4*)sQ;
        comb[4 * lane + h]     = make_float4(acc0.x*ix, acc1.x*ix, acc2.x*ix, acc3.x*ix);
        comb[4 * lane + 2 + h] = make_float4(acc0.y*iy, acc1.y*iy, acc2.y*iy, acc3.y*iy);
    }
    __syncthreads();

    // ---- phase 3: output projection, row-per-thread (wo in SGPRs) ----
    if (t < SS) {
        const float4 c0 = ((const float4*)sQ)[2 * t];      // head 0
        const float4 c1 = ((const float4*)sQ)[2 * t + 1];  // head 1
        float o[8];
#pragma unroll
        for (int i = 0; i < 8; ++i) {
            o[i] = c0.x*wo[i*8+0] + c0.y*wo[i*8+1] + c0.z*wo[i*8+2] + c0.w*wo[i*8+3]
                 + c1.x*wo[i*8+4] + c1.y*wo[i*8+5] + c1.z*wo[i*8+6] + c1.w*wo[i*8+7];
        }
        float4* o4 = (float4*)(out + (size_t)b * (SS * HID) + t * HID);
        o4[0] = make_float4(o[0], o[1], o[2], o[3]);
        o4[1] = make_float4(o[4], o[5], o[6], o[7]);
    }
}

extern "C" void kernel_launch(void* const* d_in, const int* in_sizes, int n_in,
                              void* d_out, int out_size, void* d_ws, size_t ws_size,
                              hipStream_t stream) {
    const float* query = (const float*)d_in[0];
    const float* key   = (const float*)d_in[1];
    const float* value = (const float*)d_in[2];
    const float* wq    = (const float*)d_in[3];
    const float* wk    = (const float*)d_in[4];
    const float* wv    = (const float*)d_in[5];
    const float* wo    = (const float*)d_in[6];
    float* out = (float*)d_out;
    mha_fused_kernel<<<NB, 128, 0, stream>>>(query, key, value, wq, wk, wv, wo, out);
}

// Round 8
// 119.716 us; speedup vs baseline: 1.0234x; 1.0234x over previous
//
#include <hip/hip_runtime.h>

#define NB  4096
#define SS  102
#define SSP 104
#define HID 8
#define RS  0.72134752044448170368f   // 0.5 (score scale) * log2(e), folded into q

typedef float v2f __attribute__((ext_vector_type(2)));

// dot(row8, W-row i) with W a kernel-arg pointer and i compile-time constant
// -> all W[] reads are wave-uniform: compiler emits s_load (weights live in SGPRs).
#define DOT8(A, B, W, i) \
    ((A).x*(W)[(i)*8+0] + (A).y*(W)[(i)*8+1] + (A).z*(W)[(i)*8+2] + (A).w*(W)[(i)*8+3] + \
     (B).x*(W)[(i)*8+4] + (B).y*(W)[(i)*8+5] + (B).z*(W)[(i)*8+6] + (B).w*(W)[(i)*8+7])

// LDS (10,688 B -> ~15 blocks/CU, effectively thread-cap bound):
//  sQ : [2][104][4] rotated+pre-scaled q (rows 102,103 zero).  After the q-fragment
//       loads (barrier-guarded) this region is REUSED: first as the kh=1 acc
//       partials [h][row][4], then overwritten in place with the combined,
//       normalized comb rows [h][row][4] read by phase 3.
//  sK : [2][102][4] rotated k
//  sV : [2][102][4] projected v
//  sL : [2][104] l (softmax denominator) partials of the kh=1 wave
__global__ __launch_bounds__(128) void mha_fused_kernel(
    const float* __restrict__ query, const float* __restrict__ key,
    const float* __restrict__ value, const float* __restrict__ wq,
    const float* __restrict__ wk, const float* __restrict__ wv,
    const float* __restrict__ wo, float* __restrict__ out)
{
    __shared__ float sQ[2 * SSP * 4];    // 832 floats (then partials, then comb)
    __shared__ float sK[2 * SS * 4];     // 816
    __shared__ float sV[2 * SS * 4];     // 816
    __shared__ float sL[2 * SSP];        // 208

    const int t = threadIdx.x;
    const int b = blockIdx.x;

    // ---- phase 0+1: row-per-thread load + project + rotary, all in registers ----
    // (r7 skeleton, proven: zero LDS staging, weights in SGPRs, trig under load latency)
    if (t < SS) {
        const size_t boff = (size_t)b * (SS * HID);
        const float4* q4 = (const float4*)(query + boff) + 2 * t;
        const float4* k4 = (const float4*)(key   + boff) + 2 * t;
        const float4* v4 = (const float4*)(value + boff) + 2 * t;
        const float4 qa = q4[0], qb = q4[1];
        const float4 ka = k4[0], kb = k4[1];
        const float4 va = v4[0], vb = v4[1];
        const float sn = sinf((float)t), cn = cosf((float)t);

        // reference broadcast quirk: head0 scaled by sin(row), head1 by cos(row);
        // rotary pair: e' = (e - o)*wr, o' = (o + e)*wr.  q folds RS for base-2 exp.
#pragma unroll
        for (int h = 0; h < 2; ++h) {
            const float wrk = h ? cn : sn;
            const float wrq = wrk * RS;
            float y[4], z[4];
#pragma unroll
            for (int u = 0; u < 2; ++u) {
                const int i0 = h * 4 + 2 * u;
                const float x0 = DOT8(qa, qb, wq, i0), x1 = DOT8(qa, qb, wq, i0 + 1);
                y[2*u] = (x0 - x1) * wrq;  y[2*u+1] = (x1 + x0) * wrq;
                const float k0 = DOT8(ka, kb, wk, i0), k1 = DOT8(ka, kb, wk, i0 + 1);
                z[2*u] = (k0 - k1) * wrk;  z[2*u+1] = (k1 + k0) * wrk;
            }
            ((float4*)sQ)[h * SSP + t] = make_float4(y[0], y[1], y[2], y[3]);
            ((float4*)sK)[h * SS  + t] = make_float4(z[0], z[1], z[2], z[3]);
            const float f0 = DOT8(va, vb, wv, h*4+0), f1 = DOT8(va, vb, wv, h*4+1);
            const float f2 = DOT8(va, vb, wv, h*4+2), f3 = DOT8(va, vb, wv, h*4+3);
            ((float4*)sV)[h * SS + t] = make_float4(f0, f1, f2, f3);
        }
    } else if (t < SSP) {
        // zero-pad q rows 102,103 (both heads)
        ((float4*)sQ)[t]       = make_float4(0.f, 0.f, 0.f, 0.f);
        ((float4*)sQ)[SSP + t] = make_float4(0.f, 0.f, 0.f, 0.f);
    }
    __syncthreads();

    // ---- phase 2: attention. wave = key-half kh; lanes 0-25 head0, 26-51 head1. ----
    // Each lane owns 4 q-rows (2 v2f pairs).  One ds_read_b128 per K (and V) row
    // serves 4 rows x 26 lanes x 2 heads: per-CU attention reads drop 6528 -> 3264
    // (the measured wall across rounds 0-7).  2-address broadcast is free (m136).
    const int wid = t >> 6, lane = t & 63;
    const int kh = wid;
    const bool act = lane < 52;
    const int h = (lane >= 26) ? 1 : 0;
    const int g = lane - 26 * h;          // 0..25
    const int r0 = 4 * g;                 // first of this lane's 4 rows

    v2f q[2][4];
    if (act) {
        const float4* Q4 = (const float4*)sQ + h * SSP + r0;
        const float4 f0 = Q4[0], f1 = Q4[1], f2 = Q4[2], f3 = Q4[3];
        q[0][0] = (v2f){f0.x, f1.x}; q[0][1] = (v2f){f0.y, f1.y};
        q[0][2] = (v2f){f0.z, f1.z}; q[0][3] = (v2f){f0.w, f1.w};
        q[1][0] = (v2f){f2.x, f3.x}; q[1][1] = (v2f){f2.y, f3.y};
        q[1][2] = (v2f){f2.z, f3.z}; q[1][3] = (v2f){f2.w, f3.w};
    }
    __syncthreads();   // all q reads done -> kh=1 may overlay partials into sQ

    v2f acc[2][4], l[2];
#pragma unroll
    for (int P = 0; P < 2; ++P) {
        l[P] = (v2f){0.f, 0.f};
#pragma unroll
        for (int d = 0; d < 4; ++d) acc[P][d] = (v2f){0.f, 0.f};
    }
    if (act) {
        const float4* K4 = (const float4*)sK + h * SS + 51 * kh;
        const float4* V4 = (const float4*)sV + h * SS + 51 * kh;
        // register-rotating prefetch (baseline-proven pattern)
        float4 kk = K4[0], vv = V4[0];
#pragma unroll 2
        for (int j = 1; j < 51; ++j) {
            const float4 nk = K4[j], nv = V4[j];
#pragma unroll
            for (int P = 0; P < 2; ++P) {
                v2f s = q[P][0]*kk.x + q[P][1]*kk.y + q[P][2]*kk.z + q[P][3]*kk.w;
                v2f p; p.x = __builtin_amdgcn_exp2f(s.x); p.y = __builtin_amdgcn_exp2f(s.y);
                l[P] += p;
                acc[P][0] += p*vv.x; acc[P][1] += p*vv.y;
                acc[P][2] += p*vv.z; acc[P][3] += p*vv.w;
            }
            kk = nk; vv = nv;
        }
#pragma unroll
        for (int P = 0; P < 2; ++P) {
            v2f s = q[P][0]*kk.x + q[P][1]*kk.y + q[P][2]*kk.z + q[P][3]*kk.w;
            v2f p; p.x = __builtin_amdgcn_exp2f(s.x); p.y = __builtin_amdgcn_exp2f(s.y);
            l[P] += p;
            acc[P][0] += p*vv.x; acc[P][1] += p*vv.y;
            acc[P][2] += p*vv.z; acc[P][3] += p*vv.w;
        }
    }

    // ---- kh=1 publishes raw partials into the dead-sQ overlay ----
    if (act && kh == 1) {
        float4* A = (float4*)sQ + h * SSP + r0;
        A[0] = make_float4(acc[0][0].x, acc[0][1].x, acc[0][2].x, acc[0][3].x);
        A[1] = make_float4(acc[0][0].y, acc[0][1].y, acc[0][2].y, acc[0][3].y);
        A[2] = make_float4(acc[1][0].x, acc[1][1].x, acc[1][2].x, acc[1][3].x);
        A[3] = make_float4(acc[1][0].y, acc[1][1].y, acc[1][2].y, acc[1][3].y);
        ((float4*)sL)[h * 26 + g] = make_float4(l[0].x, l[0].y, l[1].x, l[1].y);
    }
    __syncthreads();

    // ---- kh=0 combines + normalizes IN PLACE (same slots become comb rows) ----
    if (act && kh == 0) {
        float4* A = (float4*)sQ + h * SSP + r0;
        const float4 pa0 = A[0], pa1 = A[1], pa2 = A[2], pa3 = A[3];
        const float4 pl  = ((const float4*)sL)[h * 26 + g];
        const float i0 = 1.f / (l[0].x + pl.x);
        const float i1 = 1.f / (l[0].y + pl.y);
        const float i2 = 1.f / (l[1].x + pl.z);
        const float i3 = 1.f / (l[1].y + pl.w);
        A[0] = make_float4((acc[0][0].x+pa0.x)*i0, (acc[0][1].x+pa0.y)*i0,
                           (acc[0][2].x+pa0.z)*i0, (acc[0][3].x+pa0.w)*i0);
        A[1] = make_float4((acc[0][0].y+pa1.x)*i1, (acc[0][1].y+pa1.y)*i1,
                           (acc[0][2].y+pa1.z)*i1, (acc[0][3].y+pa1.w)*i1);
        A[2] = make_float4((acc[1][0].x+pa2.x)*i2, (acc[1][1].x+pa2.y)*i2,
                           (acc[1][2].x+pa2.z)*i2, (acc[1][3].x+pa2.w)*i2);
        A[3] = make_float4((acc[1][0].y+pa3.x)*i3, (acc[1][1].y+pa3.y)*i3,
                           (acc[1][2].y+pa3.z)*i3, (acc[1][3].y+pa3.w)*i3);
    }
    __syncthreads();

    // ---- phase 3: output projection, row-per-thread (wo in SGPRs) ----
    if (t < SS) {
        const float4 c0 = ((const float4*)sQ)[t];        // head 0, row t
        const float4 c1 = ((const float4*)sQ)[SSP + t];  // head 1, row t
        float o[8];
#pragma unroll
        for (int i = 0; i < 8; ++i) {
            o[i] = c0.x*wo[i*8+0] + c0.y*wo[i*8+1] + c0.z*wo[i*8+2] + c0.w*wo[i*8+3]
                 + c1.x*wo[i*8+4] + c1.y*wo[i*8+5] + c1.z*wo[i*8+6] + c1.w*wo[i*8+7];
        }
        float4* o4 = (float4*)(out + (size_t)b * (SS * HID) + t * HID);
        o4[0] = make_float4(o[0], o[1], o[2], o[3]);
        o4[1] = make_float4(o[4], o[5], o[6], o[7]);
    }
}

extern "C" void kernel_launch(void* const* d_in, const int* in_sizes, int n_in,
                              void* d_out, int out_size, void* d_ws, size_t ws_size,
                              hipStream_t stream) {
    const float* query = (const float*)d_in[0];
    const float* key   = (const float*)d_in[1];
    const float* value = (const float*)d_in[2];
    const float* wq    = (const float*)d_in[3];
    const float* wk    = (const float*)d_in[4];
    const float* wv    = (const float*)d_in[5];
    const float* wo    = (const float*)d_in[6];
    float* out = (float*)d_out;
    mha_fused_kernel<<<NB, 128, 0, stream>>>(query, key, value, wq, wk, wv, wo, out);
}